// Round 1
// baseline (9987.389 us; speedup 1.0000x reference)
//
#include <hip/hip_runtime.h>
#include <math.h>

// ---------------------------------------------------------------------------
// BivariateNormalAttention pipeline, fp32 baseline (round 0: correctness).
// Stages:
//   conv1 512->256 @112x112 +BN+ReLU          (conv_big<512,false>)
//   conv2 256->256 @112x112 +BN+ReLU +pool16  (conv_big<256,true>) -> [16,256,7,7]
//   conv3 256->128 @7x7 +BN+ReLU              (conv_small<256>)
//   conv4 128->128 @7x7 +BN+ReLU              (conv_small<128>)
//   pool 3x3 s2 -> [16,128,3,3]               (pool3x3_kernel)
//   conv5 128->64 @3x3 +BN+ReLU               (conv5_kernel)
//   fc 576->128                               (fc_kernel)
//   bivariate gaussian attention -> [16,8,56,56] (attn_kernel)
// ---------------------------------------------------------------------------

__global__ __launch_bounds__(256)
void transpose_w_kernel(const float* __restrict__ w, float* __restrict__ wT,
                        int CO, int CI)
{
    // w: [CO][CI][3][3]  ->  wT: [CI][9][CO]
    int idx = blockIdx.x * 256 + threadIdx.x;
    int n = CO * CI * 9;
    if (idx >= n) return;
    int tap = idx % 9;
    int rest = idx / 9;          // co*CI + ci
    int ci = rest % CI;
    int co = rest / CI;
    wT[(ci * 9 + tap) * CO + co] = w[idx];
}

// Big 3x3 conv at 112x112. Tile: 16x16 spatial x 64 out-channels per block.
// Thread layout: tcol(4) x trow(8) x cg(8); each thread: 8 co x 2 rows x 4 cols.
template<int CIN, bool POOL>
__global__ __launch_bounds__(256)
void conv_big_kernel(const float* __restrict__ in, const float* __restrict__ wT,
                     const float* __restrict__ gam, const float* __restrict__ bet,
                     float* __restrict__ out)
{
    constexpr int CO_TOT = 256;
    const int tile = blockIdx.x;            // 0..48
    const int ty = tile / 7, tx = tile % 7;
    const int y0 = ty * 16, x0 = tx * 16;
    const int co0 = blockIdx.y * 64;
    const int b = blockIdx.z;
    const int tid = threadIdx.x;
    const int tcol = tid & 3;
    const int trow = (tid >> 2) & 7;
    const int cg = tid >> 5;
    const int row0 = trow * 2, col0 = tcol * 4;

    __shared__ float s_in[8][18][20];  // 8 ci x (16+2) rows x 18 cols (+pad)
    __shared__ float s_w[8][9][64];    // 8 ci x 9 taps x 64 co

    float acc[8][2][4];
    #pragma unroll
    for (int a = 0; a < 8; ++a)
        #pragma unroll
        for (int r = 0; r < 2; ++r)
            #pragma unroll
            for (int c = 0; c < 4; ++c) acc[a][r][c] = 0.f;

    const float* inb = in + (size_t)b * CIN * 12544;

    for (int ci0 = 0; ci0 < CIN; ci0 += 8) {
        __syncthreads();  // protect previous iteration's LDS reads
        // stage input halo tile (zero-padded at image borders)
        for (int idx = tid; idx < 8 * 18 * 18; idx += 256) {
            int ci = idx / 324;
            int rem = idx - ci * 324;
            int r = rem / 18;
            int c = rem - r * 18;
            int yy = y0 - 1 + r;
            int xx = x0 - 1 + c;
            float v = 0.f;
            if ((unsigned)yy < 112u && (unsigned)xx < 112u)
                v = inb[(size_t)(ci0 + ci) * 12544 + yy * 112 + xx];
            s_in[ci][r][c] = v;
        }
        // stage weights (coalesced: co contiguous in wT)
        for (int idx = tid; idx < 8 * 9 * 64; idx += 256) {
            int co = idx & 63;
            int rest = idx >> 6;
            int tap = rest % 9;
            int ci = rest / 9;
            s_w[ci][tap][co] = wT[((size_t)(ci0 + ci) * 9 + tap) * CO_TOT + co0 + co];
        }
        __syncthreads();

        for (int ci = 0; ci < 8; ++ci) {
            #pragma unroll
            for (int ky = 0; ky < 3; ++ky) {
                float iv[2][8];
                #pragma unroll
                for (int r = 0; r < 2; ++r) {
                    float4 a0 = *reinterpret_cast<const float4*>(&s_in[ci][row0 + ky + r][col0]);
                    float4 a1 = *reinterpret_cast<const float4*>(&s_in[ci][row0 + ky + r][col0 + 4]);
                    iv[r][0] = a0.x; iv[r][1] = a0.y; iv[r][2] = a0.z; iv[r][3] = a0.w;
                    iv[r][4] = a1.x; iv[r][5] = a1.y; iv[r][6] = a1.z; iv[r][7] = a1.w;
                }
                float wv[3][8];
                #pragma unroll
                for (int kx = 0; kx < 3; ++kx) {
                    float4 w0 = *reinterpret_cast<const float4*>(&s_w[ci][ky * 3 + kx][cg * 8]);
                    float4 w1 = *reinterpret_cast<const float4*>(&s_w[ci][ky * 3 + kx][cg * 8 + 4]);
                    wv[kx][0] = w0.x; wv[kx][1] = w0.y; wv[kx][2] = w0.z; wv[kx][3] = w0.w;
                    wv[kx][4] = w1.x; wv[kx][5] = w1.y; wv[kx][6] = w1.z; wv[kx][7] = w1.w;
                }
                #pragma unroll
                for (int kx = 0; kx < 3; ++kx)
                    #pragma unroll
                    for (int co = 0; co < 8; ++co) {
                        float wgt = wv[kx][co];
                        #pragma unroll
                        for (int r = 0; r < 2; ++r)
                            #pragma unroll
                            for (int c = 0; c < 4; ++c)
                                acc[co][r][c] = fmaf(iv[r][kx + c], wgt, acc[co][r][c]);
                    }
            }
        }
    }

    const float kRS = 1.0f / sqrtf(1.0f + 1e-5f);  // BN: running_var=1

    if (!POOL) {
        #pragma unroll
        for (int co = 0; co < 8; ++co) {
            int cog = co0 + cg * 8 + co;
            float sc = gam[cog] * kRS;
            float bi = bet[cog];
            #pragma unroll
            for (int r = 0; r < 2; ++r) {
                float4 o4;
                o4.x = fmaxf(fmaf(acc[co][r][0], sc, bi), 0.f);
                o4.y = fmaxf(fmaf(acc[co][r][1], sc, bi), 0.f);
                o4.z = fmaxf(fmaf(acc[co][r][2], sc, bi), 0.f);
                o4.w = fmaxf(fmaf(acc[co][r][3], sc, bi), 0.f);
                size_t oidx = (((size_t)b * 256 + cog) * 112 + (y0 + row0 + r)) * 112 + x0 + col0;
                *reinterpret_cast<float4*>(&out[oidx]) = o4;
            }
        }
    } else {
        // fused BN+ReLU + 16x16 avg pool: tile == pool window exactly (112/16 == 7)
        float part[8];
        #pragma unroll
        for (int co = 0; co < 8; ++co) {
            int cog = co0 + cg * 8 + co;
            float sc = gam[cog] * kRS;
            float bi = bet[cog];
            float s = 0.f;
            #pragma unroll
            for (int r = 0; r < 2; ++r)
                #pragma unroll
                for (int c = 0; c < 4; ++c)
                    s += fmaxf(fmaf(acc[co][r][c], sc, bi), 0.f);
            part[co] = s;
        }
        __syncthreads();
        float* s_red = &s_in[0][0][0];  // reuse: need 256*9 = 2304 <= 2880 floats
        #pragma unroll
        for (int co = 0; co < 8; ++co) s_red[tid * 9 + co] = part[co];
        __syncthreads();
        if (tid < 64) {
            int cg2 = tid >> 3, co = tid & 7;
            float s = 0.f;
            for (int j = 0; j < 32; ++j) s += s_red[(cg2 * 32 + j) * 9 + co];
            out[(((size_t)b * 256 + co0 + cg2 * 8 + co) * 7 + ty) * 7 + tx] = s * (1.f / 256.f);
        }
    }
}

// Small 3x3 conv at 7x7 (pad 1). Block: 16 out-channels x one batch.
// Thread: px = tid&63 (49 active), wave handles 4 co.
template<int CIN>
__global__ __launch_bounds__(256)
void conv_small_kernel(const float* __restrict__ in, const float* __restrict__ w,
                       const float* __restrict__ gam, const float* __restrict__ bet,
                       float* __restrict__ out, int CO_TOT)
{
    const int co0 = blockIdx.x * 16;
    const int b = blockIdx.y;
    const int tid = threadIdx.x;
    const int px = tid & 63;
    const int wg = tid >> 6;
    const int py = px / 7, pxx = px - py * 7;
    const bool act = px < 49;

    __shared__ float s_in[64][9][9];   // zero-padded 7x7 -> 9x9, chunk of 64 ci
    __shared__ float s_w[64][16][9];

    float acc[4] = {0.f, 0.f, 0.f, 0.f};

    for (int ci0 = 0; ci0 < CIN; ci0 += 64) {
        __syncthreads();
        for (int idx = tid; idx < 64 * 81; idx += 256) {
            int ci = idx / 81;
            int rem = idx - ci * 81;
            int r = rem / 9, c = rem - (rem / 9) * 9;
            float v = 0.f;
            if (r >= 1 && r <= 7 && c >= 1 && c <= 7)
                v = in[((size_t)(b * CIN + ci0 + ci) * 7 + (r - 1)) * 7 + (c - 1)];
            s_in[ci][r][c] = v;
        }
        for (int idx = tid; idx < 64 * 16 * 9; idx += 256) {
            int co = idx / 576;
            int rem = idx - co * 576;
            int ci = rem / 9, tap = rem - (rem / 9) * 9;
            s_w[ci][co][tap] = w[((size_t)(co0 + co) * CIN + ci0 + ci) * 9 + tap];
        }
        __syncthreads();
        if (act) {
            for (int ci = 0; ci < 64; ++ci) {
                #pragma unroll
                for (int ky = 0; ky < 3; ++ky)
                    #pragma unroll
                    for (int kx = 0; kx < 3; ++kx) {
                        float v = s_in[ci][py + ky][pxx + kx];
                        #pragma unroll
                        for (int j = 0; j < 4; ++j)
                            acc[j] = fmaf(v, s_w[ci][wg * 4 + j][ky * 3 + kx], acc[j]);
                    }
            }
        }
    }
    if (act) {
        const float kRS = 1.0f / sqrtf(1.0f + 1e-5f);
        #pragma unroll
        for (int j = 0; j < 4; ++j) {
            int cog = co0 + wg * 4 + j;
            float v = fmaxf(fmaf(acc[j], gam[cog] * kRS, bet[cog]), 0.f);
            out[(size_t)(b * CO_TOT + cog) * 49 + py * 7 + pxx] = v;
        }
    }
}

// AdaptiveAvgPool2d((3,3)) on 7x7: windows size 3 stride 2, /9
__global__ void pool3x3_kernel(const float* __restrict__ in, float* __restrict__ out)
{
    int o = blockIdx.x * 256 + threadIdx.x;
    if (o >= 16 * 128 * 9) return;
    int xo = o % 3;
    int yo = (o / 3) % 3;
    int bc = o / 9;
    const float* p = in + (size_t)bc * 49;
    float s = 0.f;
    #pragma unroll
    for (int ky = 0; ky < 3; ++ky)
        #pragma unroll
        for (int kx = 0; kx < 3; ++kx)
            s += p[(yo * 2 + ky) * 7 + xo * 2 + kx];
    out[o] = s * (1.0f / 9.0f);
}

// conv5: 128->64 at 3x3 (pad 1) +BN+ReLU. Block = (co tile 16, batch).
__global__ __launch_bounds__(256)
void conv5_kernel(const float* __restrict__ in, const float* __restrict__ w,
                  const float* __restrict__ gam, const float* __restrict__ bet,
                  float* __restrict__ out)
{
    const int co0 = blockIdx.x * 16;
    const int b = blockIdx.y;
    const int tid = threadIdx.x;
    __shared__ float s_in[128][5][5];   // zero-padded 3x3 -> 5x5
    __shared__ float s_w[64][16][9];

    for (int idx = tid; idx < 128 * 25; idx += 256) {
        int ci = idx / 25;
        int rem = idx - ci * 25;
        int r = rem / 5, c = rem - (rem / 5) * 5;
        float v = 0.f;
        if (r >= 1 && r <= 3 && c >= 1 && c <= 3)
            v = in[((size_t)(b * 128 + ci) * 3 + (r - 1)) * 3 + (c - 1)];
        s_in[ci][r][c] = v;
    }

    float acc = 0.f;
    const int co = tid / 9;
    const int px = tid - co * 9;
    const int pyy = px / 3, pxx = px - pyy * 3;
    const bool act = tid < 144;

    for (int ci0 = 0; ci0 < 128; ci0 += 64) {
        __syncthreads();
        for (int idx = tid; idx < 64 * 16 * 9; idx += 256) {
            int c2 = idx / 576;
            int rem = idx - c2 * 576;
            int ci = rem / 9, tap = rem - (rem / 9) * 9;
            s_w[ci][c2][tap] = w[((size_t)(co0 + c2) * 128 + ci0 + ci) * 9 + tap];
        }
        __syncthreads();
        if (act) {
            for (int ci = 0; ci < 64; ++ci) {
                #pragma unroll
                for (int ky = 0; ky < 3; ++ky)
                    #pragma unroll
                    for (int kx = 0; kx < 3; ++kx)
                        acc = fmaf(s_in[ci0 + ci][pyy + ky][pxx + kx],
                                   s_w[ci][co][ky * 3 + kx], acc);
            }
        }
    }
    if (act) {
        const float kRS = 1.0f / sqrtf(1.0f + 1e-5f);
        int cog = co0 + co;
        out[(size_t)(b * 64 + cog) * 9 + px] =
            fmaxf(fmaf(acc, gam[cog] * kRS, bet[cog]), 0.f);
    }
}

// FC: feats[b][j] = sum_k h5[b][k] * wfc[j][k], k=576
__global__ void fc_kernel(const float* __restrict__ h5, const float* __restrict__ wfc,
                          float* __restrict__ feats)
{
    int o = blockIdx.x * 256 + threadIdx.x;
    if (o >= 16 * 128) return;
    int b = o >> 7, j = o & 127;
    const float* hp = h5 + b * 576;
    const float* wp = wfc + j * 576;
    float s = 0.f;
    for (int k = 0; k < 576; ++k) s = fmaf(hp[k], wp[k], s);
    feats[o] = s;
}

// Bivariate gaussian attention. One block per (b, out); 256 threads over 56x56.
__global__ __launch_bounds__(256)
void attn_kernel(const float* __restrict__ feats, const float* __restrict__ mixw,
                 float* __restrict__ out)
{
    const int bo = blockIdx.x;         // b*8 + o
    const int b = bo >> 3, o = bo & 7;
    const int tid = threadIdx.x;
    __shared__ float s_att[4][3136];
    __shared__ float s_red[4];

    // softmax(mix_w) over gmm
    float mv[4];
    float mmax = -1e30f;
    #pragma unroll
    for (int g = 0; g < 4; ++g) { mv[g] = mixw[o * 4 + g]; mmax = fmaxf(mmax, mv[g]); }
    float msum = 0.f;
    #pragma unroll
    for (int g = 0; g < 4; ++g) { mv[g] = expf(mv[g] - mmax); msum += mv[g]; }
    #pragma unroll
    for (int g = 0; g < 4; ++g) mv[g] /= msum;

    const float LOG_R = 1.0986122886681098f;  // ln(3)
    float winv[4];
    for (int g = 0; g < 4; ++g) {
        float f0 = feats[b * 128 + o * 16 + g * 4 + 0];
        float f1 = feats[b * 128 + o * 16 + g * 4 + 1];
        float f2 = feats[b * 128 + o * 16 + g * 4 + 2];
        float f3 = feats[b * 128 + o * 16 + g * 4 + 3];
        float m_x = 55.f / (1.f + expf(-f0));
        float m_y = 55.f / (1.f + expf(-f1));
        float r = expf((2.f / (1.f + expf(-f2)) - 1.f) * LOG_R);
        float rho = 1.6f / (1.f + expf(-f3)) - 0.8f;
        float denom = (-0.5f / (1.f - rho * rho)) * (1.f / 3136.f);  // sigma^2 = 56^2
        float rin = 1.f / r;

        float ssum = 0.f;
        for (int p = tid; p < 3136; p += 256) {
            int i = p / 56;
            int j = p - i * 56;
            float dx = m_x - (float)i;
            float dy = m_y - (float)j;
            float quad = dx * dx * r + dy * dy * rin - 2.f * rho * dx * dy;
            float e = expf(denom * quad);
            s_att[g][p] = e;
            ssum += e;
        }
        #pragma unroll
        for (int off = 32; off > 0; off >>= 1) ssum += __shfl_down(ssum, off);
        if ((tid & 63) == 0) s_red[tid >> 6] = ssum;
        __syncthreads();
        winv[g] = mv[g] / (s_red[0] + s_red[1] + s_red[2] + s_red[3]);
        __syncthreads();
    }

    for (int p = tid; p < 3136; p += 256) {
        float v = 0.f;
        #pragma unroll
        for (int g = 0; g < 4; ++g) v += s_att[g][p] * winv[g];
        out[(size_t)bo * 3136 + p] = v;
    }
}

extern "C" void kernel_launch(void* const* d_in, const int* in_sizes, int n_in,
                              void* d_out, int out_size, void* d_ws, size_t ws_size,
                              hipStream_t stream)
{
    const float* x    = (const float*)d_in[0];
    const float* w1   = (const float*)d_in[1];
    const float* g1   = (const float*)d_in[2];
    const float* b1   = (const float*)d_in[3];
    const float* w2   = (const float*)d_in[4];
    const float* g2   = (const float*)d_in[5];
    const float* b2   = (const float*)d_in[6];
    const float* w3   = (const float*)d_in[7];
    const float* g3   = (const float*)d_in[8];
    const float* b3   = (const float*)d_in[9];
    const float* w4   = (const float*)d_in[10];
    const float* g4   = (const float*)d_in[11];
    const float* b4   = (const float*)d_in[12];
    const float* w5   = (const float*)d_in[13];
    const float* g5   = (const float*)d_in[14];
    const float* b5   = (const float*)d_in[15];
    const float* wfc  = (const float*)d_in[16];
    const float* mixw = (const float*)d_in[17];
    float* outp = (float*)d_out;

    // workspace layout (floats), total ~53.6M floats = 214 MB
    float* ws  = (float*)d_ws;
    float* wT1 = ws;  ws += 1179648;      // 512*9*256
    float* wT2 = ws;  ws += 589824;       // 256*9*256
    float* h1  = ws;  ws += 51380224;     // 16*256*112*112
    float* p1  = ws;  ws += 200704;       // 16*256*7*7
    float* h3  = ws;  ws += 100352;       // 16*128*7*7
    float* h4  = ws;  ws += 100352;
    float* p2  = ws;  ws += 18432;        // 16*128*3*3
    float* h5  = ws;  ws += 9216;         // 16*64*3*3
    float* fts = ws;  ws += 2048;         // 16*128

    transpose_w_kernel<<<(1179648 + 255) / 256, 256, 0, stream>>>(w1, wT1, 256, 512);
    transpose_w_kernel<<<(589824 + 255) / 256, 256, 0, stream>>>(w2, wT2, 256, 256);

    conv_big_kernel<512, false><<<dim3(49, 4, 16), 256, 0, stream>>>(x, wT1, g1, b1, h1);
    conv_big_kernel<256, true ><<<dim3(49, 4, 16), 256, 0, stream>>>(h1, wT2, g2, b2, p1);

    conv_small_kernel<256><<<dim3(8, 16), 256, 0, stream>>>(p1, w3, g3, b3, h3, 128);
    conv_small_kernel<128><<<dim3(8, 16), 256, 0, stream>>>(h3, w4, g4, b4, h4, 128);

    pool3x3_kernel<<<72, 256, 0, stream>>>(h4, p2);
    conv5_kernel<<<dim3(4, 16), 256, 0, stream>>>(p2, w5, g5, b5, h5);
    fc_kernel<<<8, 256, 0, stream>>>(h5, wfc, fts);
    attn_kernel<<<128, 256, 0, stream>>>(fts, mixw, outp);
}

// Round 2
// 2282.002 us; speedup vs baseline: 4.3766x; 4.3766x over previous
//
#include <hip/hip_runtime.h>
#include <math.h>

// ---------------------------------------------------------------------------
// BivariateNormalAttention pipeline.
// Round 1: conv1/conv2 as bf16 hi/lo-split (3-pass) MFMA implicit GEMM.
//   K-order: k = tappair-chunk*32 + kg*8 + j ; tap = k>>4 (9 real + 1 zero-pad),
//            ci_local = k&15. ci-chunk = 16 per iteration.
//   A (activations) LDS: [plane(hi/lo)][halo-pix 324][16 ci] rows of 32B,
//            1-bit column swizzle by pixel parity.
//   B (weights) LDS: [plane][co 64][k 168(pad)] u16; global wprep is the exact
//            unpadded [plane][co][k160] image, staged as linear b128 copy.
//   MFMA 16x16x32_bf16; A-frag: row m=lane&15 (=x), k=(lane>>4)*8+j;
//            C/D: col=lane&15 (=co), row=(lane>>4)*4+reg (=x).
//   conv1 epilogue: BN+ReLU, split to (hi | lo<<16) u32 "packed bf16 pair" h1p.
//   conv2 epilogue: BN+ReLU + fused 16x16 avg pool (tile == pool window).
// ---------------------------------------------------------------------------

typedef __attribute__((ext_vector_type(8))) short short8v;
typedef __attribute__((ext_vector_type(4))) float f32x4;

__device__ __forceinline__ void split_bf16(float f, unsigned int& hi, unsigned int& lo)
{
    unsigned int u = __float_as_uint(f);
    hi = u >> 16;                                    // truncated bf16 hi
    float hif = __uint_as_float(u & 0xffff0000u);
    lo = __float_as_uint(f - hif) >> 16;             // residual, truncated
}

// Build wprep[cotile][chunk][plane][co 64][k 160] u16 from w[CO][CIN][3][3].
// k<144: tap=k>>4, ci=chunk*16+(k&15); k in [144,160): zero (tap-9 pad).
__global__ __launch_bounds__(256)
void prep_w_kernel(const float* __restrict__ w, unsigned short* __restrict__ wp, int CIN)
{
    int idx = blockIdx.x * 256 + threadIdx.x;
    int NCHUNK = CIN >> 4;
    int total = 4 * NCHUNK * 2 * 64 * 160;
    if (idx >= total) return;
    int k = idx % 160;
    int co = (idx / 160) & 63;
    int plane = (idx / (160 * 64)) & 1;
    int rest = idx / (160 * 64 * 2);
    int chunk = rest % NCHUNK;
    int cotile = rest / NCHUNK;
    unsigned short outv = 0;
    if (k < 144) {
        int tap = k >> 4;
        int ci = chunk * 16 + (k & 15);
        int cog = cotile * 64 + co;
        float f = w[((size_t)cog * CIN + ci) * 9 + tap];
        unsigned int hi, lo;
        split_bf16(f, hi, lo);
        outv = (unsigned short)(plane ? lo : hi);
    }
    wp[idx] = outv;
}

// POOL=false: conv1 (fp32 input x), writes packed bf16-pair h1p (u32).
// POOL=true : conv2 (packed input h1p), writes pooled fp32 [B,256,7,7].
template<int CIN, bool POOL>
__global__ __launch_bounds__(256, 2)
void conv_mfma_kernel(const void* __restrict__ in_, const unsigned short* __restrict__ wp,
                      const float* __restrict__ gam, const float* __restrict__ bet,
                      void* __restrict__ out_)
{
    constexpr int NCHUNK = CIN >> 4;
    __shared__ __align__(16) char smem[63744];
    char* sW = smem;                 // 43008 B: [plane][co 64][168 u16]
    char* sA = smem + 43008;         // 20736 B: [plane][324 pix][32 B]

    const int tid = threadIdx.x;
    const int lane = tid & 63;
    const int wv = tid >> 6;         // 4 waves
    const int m = lane & 15;         // A row within frag = x
    const int kg = lane >> 4;        // k-octet 0..3
    const int bhalf = kg & 1;        // ci half within chunk
    const int mtile = blockIdx.x;    // 0..48
    const int ty = mtile / 7, tx = mtile % 7;
    const int co0 = blockIdx.y * 64;
    const int b = blockIdx.z;

    // per-lane A read offsets per k-chunk (tap from kg>>1)
    int akc[5];
    {
        int tb = (lane >= 32) ? 1 : 0;
        #pragma unroll
        for (int kc = 0; kc < 5; ++kc) {
            int tap = kc * 2 + tb;
            if (tap > 8) tap = 8;    // padded tap-9: weights are zero
            int ky = tap / 3, kx = tap - ky * 3;
            int ap = ky * 18 + kx + m;               // halo-pix offset
            akc[kc] = ap * 32 + ((bhalf ^ (ap & 1)) << 4);
        }
    }
    const int bcol = (lane & 15) * 336 + kg * 16;

    f32x4 acc[4][4];
    #pragma unroll
    for (int i = 0; i < 4; ++i)
        #pragma unroll
        for (int j = 0; j < 4; ++j)
            acc[i][j] = (f32x4){0.f, 0.f, 0.f, 0.f};

    for (int ch = 0; ch < NCHUNK; ++ch) {
        __syncthreads();   // guard LDS overwrite vs previous K-loop reads
        // ---- stage weights: linear b128 copy, global image == LDS image (+k pad)
        {
            const uint4* g = (const uint4*)wp + (size_t)(blockIdx.y * NCHUNK + ch) * 2560;
            #pragma unroll
            for (int it = 0; it < 10; ++it) {
                int i = tid + it * 256;              // 0..2559
                uint4 t = g[i];
                int row = i / 20, col = i - row * 20;   // row = plane*64+co
                *(uint4*)(sW + (row * 21 + col) * 16) = t;
            }
        }
        // ---- stage activations: transpose [ci][pix] -> [pix][ci], split hi/lo
        for (int ps = 0; ps < 2; ++ps) {
            int pix = tid + ps * 256;
            if (pix < 324) {
                int py = pix / 18, px = pix - py * 18;
                int gy = ty * 16 + py - 1, gx = tx * 16 + px - 1;
                bool ok = ((unsigned)gy < 112u) && ((unsigned)gx < 112u);
                unsigned int hw[8], lw[8];
                if (!POOL) {
                    const float* xin = (const float*)in_ +
                        ((size_t)(b * CIN + ch * 16) * 112 + gy) * 112 + gx;
                    #pragma unroll
                    for (int c2 = 0; c2 < 8; ++c2) {
                        float f0 = ok ? xin[(size_t)(2 * c2) * 12544] : 0.f;
                        float f1 = ok ? xin[(size_t)(2 * c2 + 1) * 12544] : 0.f;
                        unsigned int h0, l0, h1, l1;
                        split_bf16(f0, h0, l0);
                        split_bf16(f1, h1, l1);
                        hw[c2] = h0 | (h1 << 16);
                        lw[c2] = l0 | (l1 << 16);
                    }
                } else {
                    const unsigned int* xin = (const unsigned int*)in_ +
                        ((size_t)(b * CIN + ch * 16) * 112 + gy) * 112 + gx;
                    #pragma unroll
                    for (int c2 = 0; c2 < 8; ++c2) {
                        unsigned int u0 = ok ? xin[(size_t)(2 * c2) * 12544] : 0u;
                        unsigned int u1 = ok ? xin[(size_t)(2 * c2 + 1) * 12544] : 0u;
                        hw[c2] = (u0 & 0xffffu) | (u1 << 16);
                        lw[c2] = (u0 >> 16) | (u1 & 0xffff0000u);
                    }
                }
                int c0 = (pix & 1) << 4, c1 = c0 ^ 16;   // parity column swizzle
                char* ph = sA + pix * 32;
                char* pl = ph + 10368;
                *(uint4*)(ph + c0) = make_uint4(hw[0], hw[1], hw[2], hw[3]);
                *(uint4*)(ph + c1) = make_uint4(hw[4], hw[5], hw[6], hw[7]);
                *(uint4*)(pl + c0) = make_uint4(lw[0], lw[1], lw[2], lw[3]);
                *(uint4*)(pl + c1) = make_uint4(lw[4], lw[5], lw[6], lw[7]);
            }
        }
        __syncthreads();
        // ---- K loop: 5 chunks of K=32 (2 taps x 16 ci each)
        #pragma unroll
        for (int kc = 0; kc < 5; ++kc) {
            short8v Ah[4], Al[4], Bh[4], Bl[4];
            #pragma unroll
            for (int mf = 0; mf < 4; ++mf) {
                const char* p = sA + (wv * 4 + mf) * 576 + akc[kc];
                Ah[mf] = *(const short8v*)p;
                Al[mf] = *(const short8v*)(p + 10368);
            }
            #pragma unroll
            for (int nf = 0; nf < 4; ++nf) {
                const char* p = sW + nf * 5376 + bcol + kc * 64;
                Bh[nf] = *(const short8v*)p;
                Bl[nf] = *(const short8v*)(p + 21504);
            }
            #pragma unroll
            for (int mf = 0; mf < 4; ++mf)
                #pragma unroll
                for (int nf = 0; nf < 4; ++nf) {
                    acc[mf][nf] = __builtin_amdgcn_mfma_f32_16x16x32_bf16(Ah[mf], Bh[nf], acc[mf][nf], 0, 0, 0);
                    acc[mf][nf] = __builtin_amdgcn_mfma_f32_16x16x32_bf16(Ah[mf], Bl[nf], acc[mf][nf], 0, 0, 0);
                    acc[mf][nf] = __builtin_amdgcn_mfma_f32_16x16x32_bf16(Al[mf], Bh[nf], acc[mf][nf], 0, 0, 0);
                }
        }
    }

    const float kRS = 1.0f / sqrtf(1.0f + 1e-5f);

    if (!POOL) {
        unsigned int* h1p = (unsigned int*)out_;
        #pragma unroll
        for (int nf = 0; nf < 4; ++nf) {
            int co = co0 + nf * 16 + (lane & 15);
            float sc = gam[co] * kRS, bi = bet[co];
            #pragma unroll
            for (int mf = 0; mf < 4; ++mf) {
                int gy = ty * 16 + wv * 4 + mf;
                int gx = tx * 16 + kg * 4;
                unsigned int pk[4];
                #pragma unroll
                for (int r = 0; r < 4; ++r) {
                    float v = fmaxf(fmaf(acc[mf][nf][r], sc, bi), 0.f);
                    unsigned int h, l;
                    split_bf16(v, h, l);
                    pk[r] = h | (l << 16);
                }
                *(uint4*)&h1p[(((size_t)b * 256 + co) * 112 + gy) * 112 + gx] =
                    make_uint4(pk[0], pk[1], pk[2], pk[3]);
            }
        }
    } else {
        __syncthreads();                      // all waves done reading sW/sA
        float* spool = (float*)smem;          // 4 waves x 4 nf x 16 co
        #pragma unroll
        for (int nf = 0; nf < 4; ++nf) {
            int co = co0 + nf * 16 + (lane & 15);
            float sc = gam[co] * kRS, bi = bet[co];
            float s = 0.f;
            #pragma unroll
            for (int mf = 0; mf < 4; ++mf)
                #pragma unroll
                for (int r = 0; r < 4; ++r)
                    s += fmaxf(fmaf(acc[mf][nf][r], sc, bi), 0.f);
            s += __shfl_xor(s, 16);
            s += __shfl_xor(s, 32);
            if (lane < 16) spool[(wv * 4 + nf) * 16 + lane] = s;
        }
        __syncthreads();
        if (tid < 64) {
            float s = 0.f;
            #pragma unroll
            for (int w2 = 0; w2 < 4; ++w2)
                s += spool[(w2 * 4 + (tid >> 4)) * 16 + (tid & 15)];
            float* p1 = (float*)out_;
            p1[(((size_t)b * 256 + co0 + tid) * 7 + ty) * 7 + tx] = s * (1.f / 256.f);
        }
    }
}

// ---------------- small downstream stages (unchanged from round 0) ----------

template<int CIN>
__global__ __launch_bounds__(256)
void conv_small_kernel(const float* __restrict__ in, const float* __restrict__ w,
                       const float* __restrict__ gam, const float* __restrict__ bet,
                       float* __restrict__ out, int CO_TOT)
{
    const int co0 = blockIdx.x * 16;
    const int b = blockIdx.y;
    const int tid = threadIdx.x;
    const int px = tid & 63;
    const int wg = tid >> 6;
    const int py = px / 7, pxx = px - py * 7;
    const bool act = px < 49;

    __shared__ float s_in[64][9][9];
    __shared__ float s_w[64][16][9];

    float acc[4] = {0.f, 0.f, 0.f, 0.f};

    for (int ci0 = 0; ci0 < CIN; ci0 += 64) {
        __syncthreads();
        for (int idx = tid; idx < 64 * 81; idx += 256) {
            int ci = idx / 81;
            int rem = idx - ci * 81;
            int r = rem / 9, c = rem - (rem / 9) * 9;
            float v = 0.f;
            if (r >= 1 && r <= 7 && c >= 1 && c <= 7)
                v = in[((size_t)(b * CIN + ci0 + ci) * 7 + (r - 1)) * 7 + (c - 1)];
            s_in[ci][r][c] = v;
        }
        for (int idx = tid; idx < 64 * 16 * 9; idx += 256) {
            int co = idx / 576;
            int rem = idx - co * 576;
            int ci = rem / 9, tap = rem - (rem / 9) * 9;
            s_w[ci][co][tap] = w[((size_t)(co0 + co) * CIN + ci0 + ci) * 9 + tap];
        }
        __syncthreads();
        if (act) {
            for (int ci = 0; ci < 64; ++ci) {
                #pragma unroll
                for (int ky = 0; ky < 3; ++ky)
                    #pragma unroll
                    for (int kx = 0; kx < 3; ++kx) {
                        float v = s_in[ci][py + ky][pxx + kx];
                        #pragma unroll
                        for (int j = 0; j < 4; ++j)
                            acc[j] = fmaf(v, s_w[ci][wg * 4 + j][ky * 3 + kx], acc[j]);
                    }
            }
        }
    }
    if (act) {
        const float kRS = 1.0f / sqrtf(1.0f + 1e-5f);
        #pragma unroll
        for (int j = 0; j < 4; ++j) {
            int cog = co0 + wg * 4 + j;
            float v = fmaxf(fmaf(acc[j], gam[cog] * kRS, bet[cog]), 0.f);
            out[(size_t)(b * CO_TOT + cog) * 49 + py * 7 + pxx] = v;
        }
    }
}

__global__ void pool3x3_kernel(const float* __restrict__ in, float* __restrict__ out)
{
    int o = blockIdx.x * 256 + threadIdx.x;
    if (o >= 16 * 128 * 9) return;
    int xo = o % 3;
    int yo = (o / 3) % 3;
    int bc = o / 9;
    const float* p = in + (size_t)bc * 49;
    float s = 0.f;
    #pragma unroll
    for (int ky = 0; ky < 3; ++ky)
        #pragma unroll
        for (int kx = 0; kx < 3; ++kx)
            s += p[(yo * 2 + ky) * 7 + xo * 2 + kx];
    out[o] = s * (1.0f / 9.0f);
}

__global__ __launch_bounds__(256)
void conv5_kernel(const float* __restrict__ in, const float* __restrict__ w,
                  const float* __restrict__ gam, const float* __restrict__ bet,
                  float* __restrict__ out)
{
    const int co0 = blockIdx.x * 16;
    const int b = blockIdx.y;
    const int tid = threadIdx.x;
    __shared__ float s_in[128][5][5];
    __shared__ float s_w[64][16][9];

    for (int idx = tid; idx < 128 * 25; idx += 256) {
        int ci = idx / 25;
        int rem = idx - ci * 25;
        int r = rem / 5, c = rem - (rem / 5) * 5;
        float v = 0.f;
        if (r >= 1 && r <= 3 && c >= 1 && c <= 3)
            v = in[((size_t)(b * 128 + ci) * 3 + (r - 1)) * 3 + (c - 1)];
        s_in[ci][r][c] = v;
    }

    float acc = 0.f;
    const int co = tid / 9;
    const int px = tid - co * 9;
    const int pyy = px / 3, pxx = px - pyy * 3;
    const bool act = tid < 144;

    for (int ci0 = 0; ci0 < 128; ci0 += 64) {
        __syncthreads();
        for (int idx = tid; idx < 64 * 16 * 9; idx += 256) {
            int c2 = idx / 576;
            int rem = idx - c2 * 576;
            int ci = rem / 9, tap = rem - (rem / 9) * 9;
            s_w[ci][c2][tap] = w[((size_t)(co0 + c2) * 128 + ci0 + ci) * 9 + tap];
        }
        __syncthreads();
        if (act) {
            for (int ci = 0; ci < 64; ++ci) {
                #pragma unroll
                for (int ky = 0; ky < 3; ++ky)
                    #pragma unroll
                    for (int kx = 0; kx < 3; ++kx)
                        acc = fmaf(s_in[ci0 + ci][pyy + ky][pxx + kx],
                                   s_w[ci][co][ky * 3 + kx], acc);
            }
        }
    }
    if (act) {
        const float kRS = 1.0f / sqrtf(1.0f + 1e-5f);
        int cog = co0 + co;
        out[(size_t)(b * 64 + cog) * 9 + px] =
            fmaxf(fmaf(acc, gam[cog] * kRS, bet[cog]), 0.f);
    }
}

__global__ void fc_kernel(const float* __restrict__ h5, const float* __restrict__ wfc,
                          float* __restrict__ feats)
{
    int o = blockIdx.x * 256 + threadIdx.x;
    if (o >= 16 * 128) return;
    int b = o >> 7, j = o & 127;
    const float* hp = h5 + b * 576;
    const float* wp = wfc + j * 576;
    float s = 0.f;
    for (int k = 0; k < 576; ++k) s = fmaf(hp[k], wp[k], s);
    feats[o] = s;
}

__global__ __launch_bounds__(256)
void attn_kernel(const float* __restrict__ feats, const float* __restrict__ mixw,
                 float* __restrict__ out)
{
    const int bo = blockIdx.x;
    const int b = bo >> 3, o = bo & 7;
    const int tid = threadIdx.x;
    __shared__ float s_att[4][3136];
    __shared__ float s_red[4];

    float mv[4];
    float mmax = -1e30f;
    #pragma unroll
    for (int g = 0; g < 4; ++g) { mv[g] = mixw[o * 4 + g]; mmax = fmaxf(mmax, mv[g]); }
    float msum = 0.f;
    #pragma unroll
    for (int g = 0; g < 4; ++g) { mv[g] = expf(mv[g] - mmax); msum += mv[g]; }
    #pragma unroll
    for (int g = 0; g < 4; ++g) mv[g] /= msum;

    const float LOG_R = 1.0986122886681098f;
    float winv[4];
    for (int g = 0; g < 4; ++g) {
        float f0 = feats[b * 128 + o * 16 + g * 4 + 0];
        float f1 = feats[b * 128 + o * 16 + g * 4 + 1];
        float f2 = feats[b * 128 + o * 16 + g * 4 + 2];
        float f3 = feats[b * 128 + o * 16 + g * 4 + 3];
        float m_x = 55.f / (1.f + expf(-f0));
        float m_y = 55.f / (1.f + expf(-f1));
        float r = expf((2.f / (1.f + expf(-f2)) - 1.f) * LOG_R);
        float rho = 1.6f / (1.f + expf(-f3)) - 0.8f;
        float denom = (-0.5f / (1.f - rho * rho)) * (1.f / 3136.f);
        float rin = 1.f / r;

        float ssum = 0.f;
        for (int p = tid; p < 3136; p += 256) {
            int i = p / 56;
            int j = p - i * 56;
            float dx = m_x - (float)i;
            float dy = m_y - (float)j;
            float quad = dx * dx * r + dy * dy * rin - 2.f * rho * dx * dy;
            float e = expf(denom * quad);
            s_att[g][p] = e;
            ssum += e;
        }
        #pragma unroll
        for (int off = 32; off > 0; off >>= 1) ssum += __shfl_down(ssum, off);
        if ((tid & 63) == 0) s_red[tid >> 6] = ssum;
        __syncthreads();
        winv[g] = mv[g] / (s_red[0] + s_red[1] + s_red[2] + s_red[3]);
        __syncthreads();
    }

    for (int p = tid; p < 3136; p += 256) {
        float v = 0.f;
        #pragma unroll
        for (int g = 0; g < 4; ++g) v += s_att[g][p] * winv[g];
        out[(size_t)bo * 3136 + p] = v;
    }
}

// ---------------------------------------------------------------------------

extern "C" void kernel_launch(void* const* d_in, const int* in_sizes, int n_in,
                              void* d_out, int out_size, void* d_ws, size_t ws_size,
                              hipStream_t stream)
{
    const float* x    = (const float*)d_in[0];
    const float* w1   = (const float*)d_in[1];
    const float* g1   = (const float*)d_in[2];
    const float* b1   = (const float*)d_in[3];
    const float* w2   = (const float*)d_in[4];
    const float* g2   = (const float*)d_in[5];
    const float* b2   = (const float*)d_in[6];
    const float* w3   = (const float*)d_in[7];
    const float* g3   = (const float*)d_in[8];
    const float* b3   = (const float*)d_in[9];
    const float* w4   = (const float*)d_in[10];
    const float* g4   = (const float*)d_in[11];
    const float* b4   = (const float*)d_in[12];
    const float* w5   = (const float*)d_in[13];
    const float* g5   = (const float*)d_in[14];
    const float* b5   = (const float*)d_in[15];
    const float* wfc  = (const float*)d_in[16];
    const float* mixw = (const float*)d_in[17];
    float* outp = (float*)d_out;

    // workspace layout (bytes): total ~212.5 MB
    char* wsb = (char*)d_ws;
    unsigned short* wprep = (unsigned short*)wsb;            // 2,621,440 u16 (reused conv1 then conv2)
    wsb += 2621440 * sizeof(unsigned short);
    unsigned int* h1p = (unsigned int*)wsb;                  // 16*256*112*112 u32
    wsb += (size_t)51380224 * 4;
    float* p1 = (float*)wsb;  wsb += 200704 * 4;             // 16*256*7*7
    float* h3 = (float*)wsb;  wsb += 100352 * 4;
    float* h4 = (float*)wsb;  wsb += 100352 * 4;
    float* p2 = (float*)wsb;  wsb += 18432 * 4;
    float* h5 = (float*)wsb;  wsb += 9216 * 4;
    float* fts = (float*)wsb; wsb += 2048 * 4;

    // conv1: prep weights (512 -> 2,621,440 u16), then MFMA conv
    prep_w_kernel<<<10240, 256, 0, stream>>>(w1, wprep, 512);
    conv_mfma_kernel<512, false><<<dim3(49, 4, 16), 256, 0, stream>>>(x, wprep, g1, b1, h1p);

    // conv2: re-prep weights into the same buffer (after conv1 consumed it)
    prep_w_kernel<<<5120, 256, 0, stream>>>(w2, wprep, 256);
    conv_mfma_kernel<256, true><<<dim3(49, 4, 16), 256, 0, stream>>>(h1p, wprep, g2, b2, p1);

    conv_small_kernel<256><<<dim3(8, 16), 256, 0, stream>>>(p1, w3, g3, b3, h3, 128);
    conv_small_kernel<128><<<dim3(8, 16), 256, 0, stream>>>(h3, w4, g4, b4, h4, 128);

    pool3x3_kernel<<<72, 256, 0, stream>>>(h4, p2);
    conv5_kernel<<<dim3(4, 16), 256, 0, stream>>>(p2, w5, g5, b5, h5);
    fc_kernel<<<8, 256, 0, stream>>>(h5, wfc, fts);
    attn_kernel<<<128, 256, 0, stream>>>(fts, mixw, outp);
}